// Round 6
// baseline (2256.741 us; speedup 1.0000x reference)
//
#include <hip/hip_runtime.h>
#include <stdint.h>
#include <stddef.h>

#define B_ 128
#define T_ 256
#define I_ 256
#define H_ 1024
#define O_ 128

typedef __attribute__((ext_vector_type(8))) __bf16 bf16x8;
typedef __attribute__((ext_vector_type(4))) float f32x4;
typedef unsigned long long u64;
typedef unsigned int u32;

// A-operand buffers are bf16 HI-ONLY, "swz8" layout:
//   element (b,k): u32 idx = (b>>4)*(K/8)*64 + (k>>3)*64 + (b&15)*4 + ((k>>1)&3)
//   u32 = bf16(k even) | bf16(k odd)<<16
// A lane's 8 k's (k = chunk*32 + q*8 + 0..7) are 4 CONTIGUOUS u32s =
// one dwordx4 (cached) or two u64 sc1 atomic loads -> zero unpack VALU,
// fragments arrive in MFMA A-order.

// ---------------------------------------------------------------- setup

__global__ void split_kernel(const float* __restrict__ src, __bf16* __restrict__ hi,
                             __bf16* __restrict__ lo, int n) {
    int i = blockIdx.x * blockDim.x + threadIdx.x;
    int stride = gridDim.x * blockDim.x;
    for (; i < n; i += stride) {
        float v = src[i];
        __bf16 h = (__bf16)v;
        hi[i] = h;
        lo[i] = (__bf16)(v - (float)h);
    }
}

// X (B,T,I) fp32 -> hi-only swz8 per t
__global__ void pack_x(const float* __restrict__ X, u32* __restrict__ xp) {
    int i = blockIdx.x * 256 + threadIdx.x;   // 0 .. T*16384-1
    int dw   = i & 3;
    int ln   = (i >> 2) & 15;
    int k8   = (i >> 6) & 31;
    int bt16 = (i >> 11) & 7;
    int t    = i >> 14;
    int k = k8 * 8 + dw * 2;
    int b = bt16 * 16 + ln;
    long xo = (long)b * T_ * I_ + (long)t * I_ + k;
    union { __bf16 b; unsigned short u; } h0, h1;
    h0.b = (__bf16)X[xo];
    h1.b = (__bf16)X[xo + 1];
    xp[(long)t * 16384 + bt16 * 2048 + k8 * 64 + ln * 4 + dw] =
        (u32)h0.u | ((u32)h1.u << 16);
}

__global__ void bias_sum_kernel(const float* __restrict__ a, const float* __restrict__ b,
                                float* __restrict__ o, int n) {
    int i = blockIdx.x * blockDim.x + threadIdx.x;
    if (i < n) o[i] = a[i] + b[i];
}

__global__ void transpose_fc(const float* __restrict__ w, float* __restrict__ wt) {
    int i = blockIdx.x * blockDim.x + threadIdx.x;
    if (i < O_ * H_) {
        int o = i / H_, k = i - o * H_;
        wt[k * O_ + o] = w[i];
    }
}

// ---------------------------------------------------------------- loaders

// sc1 LLC-coherent fragment load (mid-kernel cross-block data)
__device__ __forceinline__ bf16x8 load_frag_sc1(const u64* p) {
    union { u64 d[2]; bf16x8 v; } r;
    r.d[0] = __hip_atomic_load((u64*)p,     __ATOMIC_RELAXED, __HIP_MEMORY_SCOPE_AGENT);
    r.d[1] = __hip_atomic_load((u64*)p + 1, __ATOMIC_RELAXED, __HIP_MEMORY_SCOPE_AGENT);
    return r.v;
}

// ---------------------------------------------------------------- step
// One layer step, one 32x32 tile, W (hi+lo) register-resident, K-split 8.
// 2-term MFMA per chunk: ah*wh + ah*wl  (== ah * W_fp32 exactly).
template <int CPW, int SEG0CH, bool X0>
__device__ __forceinline__ void step_full(
    const u32* __restrict__ xA0,           // seg0 if X0 (cached plain loads)
    const u64* __restrict__ hA0,           // seg0 if !X0 (sc1)
    const u64* __restrict__ Sp,            // state (K=1024, sc1)
    const bf16x8 (&wh)[CPW][2], const bf16x8 (&wl)[CPW][2],
    const float* __restrict__ bs,
    u32* __restrict__ So, u32* __restrict__ Qo,
    int bt, int jt, int w, float* red)
{
    const int lane = threadIdx.x & 63;
    const int ln = lane & 15;
    const int q  = lane >> 4;

    f32x4 acc[2][2][2];
    #pragma unroll
    for (int s = 0; s < 2; ++s)
        #pragma unroll
        for (int n = 0; n < 2; ++n)
            #pragma unroll
            for (int r = 0; r < 2; ++r)
                acc[s][n][r] = (f32x4){0.f, 0.f, 0.f, 0.f};

    #pragma unroll
    for (int c = 0; c < CPW; ++c) {
        int gC = w * CPW + c;
        bf16x8 ah[2];
        if (gC < SEG0CH) {
            if (X0) {
                #pragma unroll
                for (int s = 0; s < 2; ++s) {
                    long off = (long)(bt * 2 + s) * (SEG0CH * 256)
                             + (gC * 4 + q) * 64 + ln * 4;
                    union { uint4 u; bf16x8 v; } r;
                    r.u = *(const uint4*)(xA0 + off);
                    ah[s] = r.v;
                }
            } else {
                #pragma unroll
                for (int s = 0; s < 2; ++s) {
                    long idx = (long)(bt * 2 + s) * (SEG0CH * 128)
                             + (gC * 4 + q) * 32 + ln * 2;
                    ah[s] = load_frag_sc1(hA0 + idx);
                }
            }
        } else {
            #pragma unroll
            for (int s = 0; s < 2; ++s) {
                long idx = (long)(bt * 2 + s) * 4096
                         + ((gC - SEG0CH) * 4 + q) * 32 + ln * 2;
                ah[s] = load_frag_sc1(Sp + idx);
            }
        }
        #pragma unroll
        for (int s = 0; s < 2; ++s)
            #pragma unroll
            for (int n = 0; n < 2; ++n) {
                acc[s][n][0] = __builtin_amdgcn_mfma_f32_16x16x32_bf16(ah[s], wh[c][n], acc[s][n][0], 0, 0, 0);
                acc[s][n][1] = __builtin_amdgcn_mfma_f32_16x16x32_bf16(ah[s], wl[c][n], acc[s][n][1], 0, 0, 0);
            }
    }

    // LDS reduce over 8 K-split waves (pad 33)
    {
        float* my = red + w * 1056;
        #pragma unroll
        for (int s = 0; s < 2; ++s)
            #pragma unroll
            for (int n = 0; n < 2; ++n) {
                f32x4 sum = acc[s][n][0] + acc[s][n][1];
                #pragma unroll
                for (int r = 0; r < 4; ++r)       // C/D: col=ln, row=q*4+r
                    my[(s * 16 + q * 4 + r) * 33 + n * 16 + ln] = sum[r];
            }
    }
    __syncthreads();

    // epilogue: 1024 outputs = 512 u32 k-pairs, one per thread
    {
        int tid = threadIdx.x;
        int row = tid & 31;
        int jp  = tid >> 5;                 // 0..15
        int c0 = jp * 2;
        float v0 = 0.f, v1 = 0.f;
        #pragma unroll
        for (int w8 = 0; w8 < 8; ++w8) {
            v0 += red[w8 * 1056 + row * 33 + c0];
            v1 += red[w8 * 1056 + row * 33 + c0 + 1];
        }
        int j0 = jt * 32 + c0;
        float h0 = tanhf(v0 + bs[j0]);
        float h1v = tanhf(v1 + bs[j0 + 1]);
        union { __bf16 b; unsigned short u; } a0, a1;
        a0.b = (__bf16)h0;
        a1.b = (__bf16)h1v;
        u32 pk = (u32)a0.u | ((u32)a1.u << 16);
        int bgrp = bt * 2 + (row >> 4);
        long uidx = (long)bgrp * 8192 + (jt * 4 + (jp >> 2)) * 64
                  + (row & 15) * 4 + (jp & 3);
        __hip_atomic_store(&So[uidx], pk, __ATOMIC_RELAXED, __HIP_MEMORY_SCOPE_AGENT);
        if (Qo)
            __hip_atomic_store(&Qo[uidx], pk, __ATOMIC_RELAXED, __HIP_MEMORY_SCOPE_AGENT);
    }
}

// ---------------------------------------------------------------- barriers
// Fence-free relaxed-atomic cohort barrier (128 blocks = 8 grps x 16).
// bar layout (u32): cohort c at c*1024: [g*32]=arrive, [256]=super,
// [512+g*32]=release; prog0 replicas at [2048+g*32].
__device__ __forceinline__ void cohort_barrier(unsigned* bar, int cohort, int grp,
                                               unsigned tgt, bool pub_prog) {
    asm volatile("s_waitcnt vmcnt(0)" ::: "memory");
    __syncthreads();
    if (threadIdx.x == 0) {
        unsigned* base = bar + cohort * 1024;
        unsigned old = __hip_atomic_fetch_add(&base[grp * 32], 1u, __ATOMIC_RELAXED,
                                              __HIP_MEMORY_SCOPE_AGENT);
        if ((old & 15u) == 15u) {
            unsigned so = __hip_atomic_fetch_add(&base[256], 1u, __ATOMIC_RELAXED,
                                                 __HIP_MEMORY_SCOPE_AGENT);
            if ((so & 7u) == 7u) {
                #pragma unroll
                for (int g = 0; g < 8; ++g)
                    __hip_atomic_store(&base[512 + g * 32], tgt, __ATOMIC_RELAXED,
                                       __HIP_MEMORY_SCOPE_AGENT);
                if (pub_prog) {
                    #pragma unroll
                    for (int g = 0; g < 8; ++g)
                        __hip_atomic_store(&bar[2048 + g * 32], tgt, __ATOMIC_RELAXED,
                                           __HIP_MEMORY_SCOPE_AGENT);
                }
            }
        }
        while (__hip_atomic_load(&base[512 + grp * 32], __ATOMIC_RELAXED,
                                 __HIP_MEMORY_SCOPE_AGENT) < tgt)
            __builtin_amdgcn_s_sleep(2);
    }
    __syncthreads();
    asm volatile("" ::: "memory");
}

// ---------------------------------------------------------------- persistent
struct PArgs {
    const u32* xp;                        // hi-only swz8 X, per-t stride 16384 u32
    const __bf16 *Wi0h, *Wi0l, *Wr0h, *Wr0l;
    const __bf16 *Wi1h, *Wi1l, *Wr1h, *Wr1l;
    const float *bs0, *bs1;
    u32 *h1;                              // hi-only swz8, per-t stride 65536 u32
    u32 *s0a, *s0b, *s1a, *s1b;           // hi-only swz8 states (65536 u32 each)
    unsigned* bar;
};

// 256 blocks x 512 threads (8 waves), 1/CU. Blocks 0..127 = layer0 cohort,
// 128..255 = layer1 cohort. Tiles per layer: 4 bt (m=32) x 32 jt (n=32).
// Layer0 free-runs; layer1 waits on prog0 (one-way producer flag).
__global__ __launch_bounds__(512, 2) void persistent_rnn(PArgs a) {
    __shared__ float red[8 * 1056];
    const int w = threadIdx.x >> 6;
    const int lane = threadIdx.x & 63;
    const int ln = lane & 15;
    const int q  = lane >> 4;
    const int layer = blockIdx.x >> 7;
    const int r7 = blockIdx.x & 127;
    const int grp = r7 & 7;
    const int jt = r7 & 31;
    const int bt = r7 >> 5;

    if (layer == 0) {
        bf16x8 wh[5][2], wl[5][2];        // Ktot=1280: 40 chunks, 5/wave
        #pragma unroll
        for (int c = 0; c < 5; ++c) {
            int gC = w * 5 + c;
            #pragma unroll
            for (int n = 0; n < 2; ++n) {
                int jr = jt * 32 + n * 16 + ln;
                if (gC < 8) {
                    wh[c][n] = *(const bf16x8*)(a.Wi0h + (long)jr * 256 + gC * 32 + q * 8);
                    wl[c][n] = *(const bf16x8*)(a.Wi0l + (long)jr * 256 + gC * 32 + q * 8);
                } else {
                    wh[c][n] = *(const bf16x8*)(a.Wr0h + (long)jr * 1024 + (gC - 8) * 32 + q * 8);
                    wl[c][n] = *(const bf16x8*)(a.Wr0l + (long)jr * 1024 + (gC - 8) * 32 + q * 8);
                }
            }
        }
        for (int t = 0; t < T_; ++t) {
            const u32* sin = (t & 1) ? a.s0b : a.s0a;
            u32* sout      = (t & 1) ? a.s0a : a.s0b;
            step_full<5, 8, true>(a.xp + (long)t * 16384, (const u64*)nullptr,
                                  (const u64*)sin, wh, wl, a.bs0,
                                  sout, a.h1 + (long)t * 65536, bt, jt, w, red);
            cohort_barrier(a.bar, 0, grp, (unsigned)(t + 1), true);
        }
    } else {
        bf16x8 wh[8][2], wl[8][2];        // Ktot=2048: 64 chunks, 8/wave
        #pragma unroll
        for (int c = 0; c < 8; ++c) {
            int gC = w * 8 + c;
            #pragma unroll
            for (int n = 0; n < 2; ++n) {
                int jr = jt * 32 + n * 16 + ln;
                if (gC < 32) {
                    wh[c][n] = *(const bf16x8*)(a.Wi1h + (long)jr * 1024 + gC * 32 + q * 8);
                    wl[c][n] = *(const bf16x8*)(a.Wi1l + (long)jr * 1024 + gC * 32 + q * 8);
                } else {
                    wh[c][n] = *(const bf16x8*)(a.Wr1h + (long)jr * 1024 + (gC - 32) * 32 + q * 8);
                    wl[c][n] = *(const bf16x8*)(a.Wr1l + (long)jr * 1024 + (gC - 32) * 32 + q * 8);
                }
            }
        }
        for (int t1 = 0; t1 < T_; ++t1) {
            // wait for layer0 to finish step t1 (h1[t1] fully at LLC)
            if (threadIdx.x == 0) {
                while (__hip_atomic_load(&a.bar[2048 + grp * 32], __ATOMIC_RELAXED,
                                         __HIP_MEMORY_SCOPE_AGENT) < (unsigned)(t1 + 1))
                    __builtin_amdgcn_s_sleep(2);
            }
            __syncthreads();
            const u32* sin = (t1 & 1) ? a.s1b : a.s1a;
            u32* sout      = (t1 & 1) ? a.s1a : a.s1b;
            step_full<8, 32, false>((const u32*)nullptr,
                                    (const u64*)(a.h1 + (long)t1 * 65536),
                                    (const u64*)sin, wh, wl, a.bs1,
                                    sout, (u32*)nullptr, bt, jt, w, red);
            cohort_barrier(a.bar, 1, grp, (unsigned)(t1 + 1), false);
        }
    }
}

// ---------------------------------------------------------------- final FC
__global__ __launch_bounds__(128) void fc_kernel(const u32* __restrict__ sp,
                                                 const float* __restrict__ wt,
                                                 const float* __restrict__ bfc,
                                                 float* __restrict__ out) {
    int b = blockIdx.x;
    int o = threadIdx.x;
    int bgrp = b >> 4, ln = b & 15;
    float acc = 0.f;
    #pragma unroll 4
    for (int kp = 0; kp < H_ / 2; ++kp) {
        u32 v = sp[(long)bgrp * 8192 + (kp >> 2) * 64 + ln * 4 + (kp & 3)];
        union { unsigned short u; __bf16 bf; } e0, e1;
        e0.u = (unsigned short)(v & 0xFFFF);
        e1.u = (unsigned short)(v >> 16);
        acc += (float)e0.bf * wt[(2 * kp) * O_ + o]
             + (float)e1.bf * wt[(2 * kp + 1) * O_ + o];
    }
    out[b * O_ + o] = acc + bfc[o];
}

// ---------------------------------------------------------------- launch

extern "C" void kernel_launch(void* const* d_in, const int* in_sizes, int n_in,
                              void* d_out, int out_size, void* d_ws, size_t ws_size,
                              hipStream_t stream) {
    const float* X     = (const float*)d_in[0];
    const float* Wih0  = (const float*)d_in[1];
    const float* Whh0  = (const float*)d_in[2];
    const float* bih0  = (const float*)d_in[3];
    const float* bhh0  = (const float*)d_in[4];
    const float* Wih1  = (const float*)d_in[5];
    const float* Whh1  = (const float*)d_in[6];
    const float* bih1  = (const float*)d_in[7];
    const float* bhh1  = (const float*)d_in[8];
    const float* Wfc   = (const float*)d_in[9];
    const float* bfc   = (const float*)d_in[10];
    float* out = (float*)d_out;

    char* p = (char*)d_ws;
    auto alloc = [&](size_t bytes) -> void* {
        void* r = (void*)p;
        p += (bytes + 255) & ~(size_t)255;
        return r;
    };
    const size_t nW0 = (size_t)H_ * I_;
    const size_t nW  = (size_t)H_ * H_;
    u32* xp      = (u32*)alloc((size_t)T_ * 16384 * 4);     // 16.8 MB
    __bf16* W0h  = (__bf16*)alloc(nW0 * 2);
    __bf16* W0l  = (__bf16*)alloc(nW0 * 2);
    __bf16* Wh0h = (__bf16*)alloc(nW * 2);
    __bf16* Wh0l = (__bf16*)alloc(nW * 2);
    __bf16* Wi1h = (__bf16*)alloc(nW * 2);
    __bf16* Wi1l = (__bf16*)alloc(nW * 2);
    __bf16* Wh1h = (__bf16*)alloc(nW * 2);
    __bf16* Wh1l = (__bf16*)alloc(nW * 2);
    u32* h1   = (u32*)alloc((size_t)T_ * 65536 * 4);        // 67 MB
    u32* s0a  = (u32*)alloc(65536 * 4);
    u32* s0b  = (u32*)alloc(65536 * 4);
    u32* s1a  = (u32*)alloc(65536 * 4);
    u32* s1b  = (u32*)alloc(65536 * 4);
    float* wfct = (float*)alloc((size_t)H_ * O_ * 4);
    float* bs0  = (float*)alloc((size_t)H_ * 4);
    float* bs1  = (float*)alloc((size_t)H_ * 4);
    unsigned* bar = (unsigned*)alloc(16384);
    (void)ws_size; (void)n_in; (void)in_sizes; (void)out_size;

    pack_x<<<16384, 256, 0, stream>>>(X, xp);
    split_kernel<<<512, 256, 0, stream>>>(Wih0, W0h, W0l, (int)nW0);
    split_kernel<<<1024, 256, 0, stream>>>(Whh0, Wh0h, Wh0l, (int)nW);
    split_kernel<<<1024, 256, 0, stream>>>(Wih1, Wi1h, Wi1l, (int)nW);
    split_kernel<<<1024, 256, 0, stream>>>(Whh1, Wh1h, Wh1l, (int)nW);
    bias_sum_kernel<<<4, 256, 0, stream>>>(bih0, bhh0, bs0, H_);
    bias_sum_kernel<<<4, 256, 0, stream>>>(bih1, bhh1, bs1, H_);
    transpose_fc<<<(O_ * H_ + 255) / 256, 256, 0, stream>>>(Wfc, wfct);

    hipMemsetAsync(s0a, 0, 65536 * 4, stream);
    hipMemsetAsync(s1a, 0, 65536 * 4, stream);
    hipMemsetAsync(bar, 0, 16384, stream);

    PArgs args;
    args.xp = xp;
    args.Wi0h = W0h; args.Wi0l = W0l; args.Wr0h = Wh0h; args.Wr0l = Wh0l;
    args.Wi1h = Wi1h; args.Wi1l = Wi1l; args.Wr1h = Wh1h; args.Wr1l = Wh1l;
    args.bs0 = bs0; args.bs1 = bs1;
    args.h1 = h1;
    args.s0a = s0a; args.s0b = s0b; args.s1a = s1a; args.s1b = s1b;
    args.bar = bar;
    void* kp[] = { &args };
    hipLaunchCooperativeKernel((void*)persistent_rnn, dim3(256), dim3(512), kp, 0, stream);

    // final layer1 state: last t1=255 (odd) wrote s1a
    fc_kernel<<<B_, O_, 0, stream>>>(s1a, wfct, bfc, out);
}